// Round 8
// baseline (355.005 us; speedup 1.0000x reference)
//
#include <hip/hip_runtime.h>
#include <math.h>

// GAU attention: LN -> silu(x@W^T+b) x4 -> P=relu^2(QK^T/sqrt(T)) -> AV=P@V -> (U*AV)@Wo^T+bo
// R8: R7 (barrier-free register streaming, XCD remap) + deeper software pipeline:
//   - B operand triple-buffered: b[kf%3] refilled for kf+3 right after last use
//     -> issue-to-use ~3 MFMA blocks.
//   - A refill staggered per-row inside the MFMA block (after row mi's last read)
//     -> effective distance ~2 blocks, zero extra registers.
//   - K-loop in explicit 6-iter chunks, all buffer indices literal (no scratch).

typedef __attribute__((ext_vector_type(8))) short short8;
typedef __attribute__((ext_vector_type(4))) float floatx4;

constexpr int HD = 768;
constexpr int TT = 2048;
constexpr long WElem = 589824;     // 768*768
constexpr long QKpb  = 1572864;    // 2048*768 shorts per batch
constexpr long Ppb   = 4194304;    // 2048*2048 shorts per batch

__device__ __forceinline__ short f2bf(float x) {
  unsigned u = __builtin_bit_cast(unsigned, x);
  u = u + 0x7fffu + ((u >> 16) & 1u);   // RNE
  return (short)(u >> 16);
}
__device__ __forceinline__ float bf2f(short s) {
  unsigned u = ((unsigned)(unsigned short)s) << 16;
  return __builtin_bit_cast(float, u);
}

// Packed fragment-order offset (in shorts) of element (i, c) of a row-major
// [R x C] matrix, CF = C/32. Fragment (i>>4, c>>5) is 512 shorts (1KB), lane-major.
__device__ __forceinline__ long p16(int i, int c, int CF) {
  return ((long)((i >> 4) * CF + (c >> 5))) * 512 +
         ((c & 31) >> 3) * 128 + (i & 15) * 8 + (c & 7);
}

// ---------------- LayerNorm + bf16 cast, writes x in packed-frag order ------------
__global__ __launch_bounds__(256) void ln_kernel(
    const float* __restrict__ x, const float* __restrict__ g,
    const float* __restrict__ b, short* __restrict__ out) {
  int row = blockIdx.x;
  const float* xr = x + (long)row * HD;
  int t = threadIdx.x;
  float v0 = xr[t], v1 = xr[t + 256], v2 = xr[t + 512];
  float s = v0 + v1 + v2;
  float ss = v0 * v0 + v1 * v1 + v2 * v2;
#pragma unroll
  for (int o = 32; o > 0; o >>= 1) {
    s += __shfl_down(s, o);
    ss += __shfl_down(ss, o);
  }
  __shared__ float red[8];
  int wid = t >> 6;
  if ((t & 63) == 0) { red[wid] = s; red[4 + wid] = ss; }
  __syncthreads();
  float S = red[0] + red[1] + red[2] + red[3];
  float SS = red[4] + red[5] + red[6] + red[7];
  float mean = S * (1.0f / HD);
  float var = SS * (1.0f / HD) - mean * mean;
  float rstd = rsqrtf(var + 1e-5f);
  out[p16(row, t, 24)]       = f2bf((v0 - mean) * rstd * g[t]       + b[t]);
  out[p16(row, t + 256, 24)] = f2bf((v1 - mean) * rstd * g[t + 256] + b[t + 256]);
  out[p16(row, t + 512, 24)] = f2bf((v2 - mean) * rstd * g[t + 512] + b[t + 512]);
}

// ---------------- fp32 -> packed bf16 weights + bias concat ------------------------
__global__ __launch_bounds__(256) void convert_kernel(
    const float* __restrict__ wu, const float* __restrict__ wq,
    const float* __restrict__ wk, const float* __restrict__ wv,
    const float* __restrict__ wo,
    const float* __restrict__ bu, const float* __restrict__ bq,
    const float* __restrict__ bk, const float* __restrict__ bv,
    short* __restrict__ Wb, float* __restrict__ bcat) {
  long i = (long)blockIdx.x * 256 + threadIdx.x;
  if (i < 5 * WElem) {
    int which = (int)(i / WElem);
    long off = i - (long)which * WElem;
    const float* src = which == 0 ? wu : which == 1 ? wq : which == 2 ? wk
                     : which == 3 ? wv : wo;
    int n = (int)(off / HD), k = (int)(off - (long)n * HD);
    Wb[(long)which * WElem + p16(n, k, 24)] = f2bf(src[off]);
  }
  if (i < 4 * HD) {
    int which = (int)(i / HD);
    int off = (int)(i - which * HD);
    const float* src = which == 0 ? bu : which == 1 ? bq : which == 2 ? bk : bv;
    bcat[i] = src[off];
  }
}

// ---------------- barrier-free streaming GEMM, 4 waves (2x2), wave tile 64x64 ------
// 1-D grid, XCD-aware decode (flat%8 = XCD owns a contiguous by-stripe).
// A dbuf + staggered refill; B 3-buf dist-3. No LDS, no __syncthreads in K-loop.
template <int EPI, int KF, int GZ>
__global__ __launch_bounds__(256, 3) void wgemm(
    const short* __restrict__ Ag, const short* __restrict__ Bg,
    long sAz, long sBz,
    short* __restrict__ o0, short* __restrict__ o1,
    short* __restrict__ o2, short* __restrict__ o3,
    float* __restrict__ outf, const float* __restrict__ bias,
    const short* __restrict__ umul) {
  constexpr int TM = 4, TN = 4;
  int f = blockIdx.x;
  int xcd = f & 7, i = f >> 3;
  int bx = i >> 3, byo = i & 7;
  int z, by;
  if constexpr (GZ == 1) { z = 0;        by = xcd * 8 + byo; }
  else                   { z = xcd >> 1; by = (xcd & 1) * 8 + byo; }

  int t = threadIdx.x, w = t >> 6, lane = t & 63;
  int qd = lane >> 4, l15 = lane & 15;
  int mf0 = (by * 2 + (w >> 1)) * TM;
  int nf0 = (bx * 2 + (w & 1)) * TN;
  const short* aB = Ag + (long)z * sAz + (long)mf0 * KF * 512 + lane * 8;
  const short* bB = Bg + (long)z * sBz + (long)nf0 * KF * 512 + lane * 8;

  floatx4 acc[TM][TN] = {};
  short8 a[2][TM], b[3][TN];

#define LDA_(pa, kf2, mi) a[pa][mi] = *(const short8*)(aB + (mi * KF + (kf2)) * 512);
#define LDB_(pb, kf3)                                                       \
  { _Pragma("unroll") for (int ni = 0; ni < TN; ni++)                       \
        b[pb][ni] = *(const short8*)(bB + (ni * KF + (kf3)) * 512); }
#define MROW_(pa, pb, mi)                                                   \
  { _Pragma("unroll") for (int ni = 0; ni < TN; ni++)                       \
        acc[mi][ni] = __builtin_amdgcn_mfma_f32_16x16x32_bf16(              \
            a[pa][mi], b[pb][ni], acc[mi][ni], 0, 0, 0); }
  // one K-iteration: 16 MFMA with A-refill (kf+2) staggered per row,
  // then B-refill (kf+3) into the buffer just freed.
#define KITER_(kf, pa, pb, doA, doB)                                        \
  { MROW_(pa, pb, 0) if (doA) { LDA_(pa, (kf) + 2, 0) }                     \
    MROW_(pa, pb, 1) if (doA) { LDA_(pa, (kf) + 2, 1) }                     \
    MROW_(pa, pb, 2) if (doA) { LDA_(pa, (kf) + 2, 2) }                     \
    MROW_(pa, pb, 3) if (doA) { LDA_(pa, (kf) + 2, 3) }                     \
    if (doB) { LDB_(pb, (kf) + 3) } }

  // prologue, oldest-needed first
  LDB_(0, 0) LDA_(0, 0, 0) LDA_(0, 0, 1) LDA_(0, 0, 2) LDA_(0, 0, 3)
  LDB_(1, 1) LDA_(1, 1, 0) LDA_(1, 1, 1) LDA_(1, 1, 2) LDA_(1, 1, 3)
  LDB_(2, 2)

  constexpr int NCH = (KF - 4) / 6;   // full 6-iter chunks (all refills in-range)
  for (int c = 0; c < NCH; ++c) {
    int kf = c * 6;
    KITER_(kf + 0, 0, 0, true, true)
    KITER_(kf + 1, 1, 1, true, true)
    KITER_(kf + 2, 0, 2, true, true)
    KITER_(kf + 3, 1, 0, true, true)
    KITER_(kf + 4, 0, 1, true, true)
    KITER_(kf + 5, 1, 2, true, true)
  }
  constexpr int R = KF - NCH * 6;     // 4..9 tail iters, guards fold at compile time
#pragma unroll
  for (int j = 0; j < R; ++j) {
    int kf = NCH * 6 + j;             // NCH*6 divisible by 6 -> pa=j&1, pb=j%3 fold
    KITER_(kf, (j & 1), (j % 3), (j < R - 2), (j < R - 3))
  }
#undef LDA_
#undef LDB_
#undef MROW_
#undef KITER_

  // epilogue: lane holds D[row = qd*4+r][col = l15] per 16x16 frag
#pragma unroll
  for (int mi = 0; mi < TM; mi++)
#pragma unroll
    for (int ni = 0; ni < TN; ni++) {
      int mB = (mf0 + mi) * 16 + qd * 4;
      int col = (nf0 + ni) * 16 + l15;
#pragma unroll
      for (int r = 0; r < 4; r++) {
        int m = mB + r;
        float v = acc[mi][ni][r];
        if constexpr (EPI == 0) {
          v += bias[col];
          v = v / (1.0f + __expf(-v));  // silu
          short sv = f2bf(v);
          int which = col / HD;
          int d = col - which * HD;
          int batch = m >> 11, ii = m & (TT - 1);
          if (which == 0)      o0[(long)m * HD + d] = sv;                      // U row-major
          else if (which == 1) o1[(long)batch * QKpb + p16(ii, d, 24)] = sv;   // Q pack
          else if (which == 2) o2[(long)batch * QKpb + p16(ii, d, 24)] = sv;   // K pack
          else                 o3[(long)batch * QKpb + p16(d, ii, 64)] = sv;   // Vt pack
        } else if constexpr (EPI == 1) {
          v *= 0.022097086912079608f;   // 1/sqrt(2048)
          v = fmaxf(v, 0.0f);
          v = v * v;
          o0[(long)z * Ppb + p16(m, col, 64)] = f2bf(v);                       // P pack
        } else if constexpr (EPI == 2) {
          long gm = (long)z * TT + m;
          float um = bf2f(umul[gm * HD + col]);
          o0[p16((int)gm, col, 24)] = f2bf(v * um);                            // G pack
        } else {
          outf[(long)m * HD + col] = v + bias[col];
        }
      }
    }
}

extern "C" void kernel_launch(void* const* d_in, const int* in_sizes, int n_in,
                              void* d_out, int out_size, void* d_ws, size_t ws_size,
                              hipStream_t stream) {
  (void)in_sizes; (void)n_in; (void)out_size; (void)ws_size;
  const float* hid = (const float*)d_in[0];
  const float* lng = (const float*)d_in[1];
  const float* lnb = (const float*)d_in[2];
  const float* Wu  = (const float*)d_in[3];
  const float* bu  = (const float*)d_in[4];
  const float* Wq  = (const float*)d_in[5];
  const float* bq  = (const float*)d_in[6];
  const float* Wk  = (const float*)d_in[7];
  const float* bk  = (const float*)d_in[8];
  const float* Wv  = (const float*)d_in[9];
  const float* bv  = (const float*)d_in[10];
  const float* Wo  = (const float*)d_in[11];
  const float* bo  = (const float*)d_in[12];

  // workspace layout (bytes); packed buffers
  char* ws = (char*)d_ws;
  short* Wb   = (short*)(ws);                 // 5*589824 bf16 = 5,898,240 B (packed)
  float* bcat = (float*)(ws + 5898240);       // 3072 fp32     =    12,288 B
  short* xbf  = (short*)(ws + 5910528);       // x pack, 12,582,912 B
  short* Ub   = (short*)(ws + 18493440);      // U row-major, 12,582,912 B
  short* Qb   = (short*)(ws + 31076352);      // Q pack, 12,582,912 B
  short* Kb   = (short*)(ws + 43659264);      // K pack, 12,582,912 B
  short* Vt   = (short*)(ws + 56242176);      // Vt pack, 12,582,912 B
  short* Pb   = (short*)(ws + 68825088);      // P pack, 33,554,432 B
  short* Gb   = (short*)(ws + 102379520);     // G pack, 12,582,912 B (total ~115 MB)

  convert_kernel<<<11520, 256, 0, stream>>>(Wu, Wq, Wk, Wv, Wo, bu, bq, bk, bv, Wb, bcat);
  ln_kernel<<<8192, 256, 0, stream>>>(hid, lng, lnb, xbf);

  // U,Q,K,V = silu(x @ Wcat^T + bcat): M=8192 (GY=64), N=3072 (GX=24), K=768
  wgemm<0, 24, 1><<<1536, 256, 0, stream>>>(
      xbf, Wb, 0, 0, Ub, Qb, Kb, Vt, nullptr, bcat, nullptr);

  // P = relu(QK^T/sqrt(T))^2 per batch: GY=16, GX=16, GZ=4, K=768
  wgemm<1, 24, 4><<<1024, 256, 0, stream>>>(
      Qb, Kb, QKpb, QKpb, Pb, nullptr, nullptr, nullptr, nullptr, nullptr, nullptr);

  // G = (P @ V) * U per batch: GY=16, GX=6, GZ=4, K=2048
  wgemm<2, 64, 4><<<384, 256, 0, stream>>>(
      Pb, Vt, Ppb, QKpb, Gb, nullptr, nullptr, nullptr, nullptr, nullptr, Ub);

  // out = G @ Wo^T + bo: GY=64, GX=6, GZ=1, K=768, fp32 out
  wgemm<3, 24, 1><<<384, 256, 0, stream>>>(
      Gb, Wb + 4 * WElem, 0, 0, nullptr, nullptr, nullptr, nullptr,
      (float*)d_out, bo, nullptr);
}

// Round 9
// 276.319 us; speedup vs baseline: 1.2848x; 1.2848x over previous
//
#include <hip/hip_runtime.h>
#include <math.h>

// GAU attention: LN -> silu(x@W^T+b) x4 -> P=relu^2(QK^T/sqrt(T)) -> AV=P@V -> (U*AV)@Wo^T+bo
// R9: R7 loop (ping-pong dist-2, barrier-free register streaming, XCD remap) +
//   - kf-major fragment packing (pL): the 4 frags a wave loads at step kf are
//     contiguous (4KB) -> imm-offset loads + one pointer bump per iter
//     (cuts K-loop addressing VALU ~4x; R7 showed VALUBusy 36% vs MfmaUtil 20%).
//   - TN=2 (wave 64x32) for the N=768 GEMMs (AV, out) -> 768 blocks, 3 blocks/CU
//     (R7 ran them at 1.5 blocks/CU).
// R8 lesson: deeper buffering spills (VGPR ceiling) — do NOT deepen the pipeline.

typedef __attribute__((ext_vector_type(8))) short short8;
typedef __attribute__((ext_vector_type(4))) float floatx4;

constexpr int HD = 768;
constexpr int TT = 2048;
constexpr long WElem = 589824;     // 768*768
constexpr long QKpb  = 1572864;    // 2048*768 shorts per batch
constexpr long Ppb   = 4194304;    // 2048*2048 shorts per batch

__device__ __forceinline__ short f2bf(float x) {
  unsigned u = __builtin_bit_cast(unsigned, x);
  u = u + 0x7fffu + ((u >> 16) & 1u);   // RNE
  return (short)(u >> 16);
}
__device__ __forceinline__ float bf2f(short s) {
  unsigned u = ((unsigned)(unsigned short)s) << 16;
  return __builtin_bit_cast(float, u);
}

// kf-major packed offset (in shorts) of element (i, c) of a row-major [R x C]
// matrix, KF = C/32. Layout: [strip = i>>6][kf = c>>5][frag mi = (i>>4)&3][512].
// Within-frag: lane = ((c&31)>>3)*16 + (i&15), elem = c&7.
// A wave's 4 frags at step kf are contiguous (4KB) -> imm-offset loads.
__device__ __forceinline__ long pL(int i, int c, int KF) {
  return (((long)(i >> 6) * KF + (c >> 5)) * 4 + ((i >> 4) & 3)) * 512 +
         ((c & 31) >> 3) * 128 + (i & 15) * 8 + (c & 7);
}

// ---------------- LayerNorm + bf16 cast, writes x in packed-frag order ------------
__global__ __launch_bounds__(256) void ln_kernel(
    const float* __restrict__ x, const float* __restrict__ g,
    const float* __restrict__ b, short* __restrict__ out) {
  int row = blockIdx.x;
  const float* xr = x + (long)row * HD;
  int t = threadIdx.x;
  float v0 = xr[t], v1 = xr[t + 256], v2 = xr[t + 512];
  float s = v0 + v1 + v2;
  float ss = v0 * v0 + v1 * v1 + v2 * v2;
#pragma unroll
  for (int o = 32; o > 0; o >>= 1) {
    s += __shfl_down(s, o);
    ss += __shfl_down(ss, o);
  }
  __shared__ float red[8];
  int wid = t >> 6;
  if ((t & 63) == 0) { red[wid] = s; red[4 + wid] = ss; }
  __syncthreads();
  float S = red[0] + red[1] + red[2] + red[3];
  float SS = red[4] + red[5] + red[6] + red[7];
  float mean = S * (1.0f / HD);
  float var = SS * (1.0f / HD) - mean * mean;
  float rstd = rsqrtf(var + 1e-5f);
  out[pL(row, t, 24)]       = f2bf((v0 - mean) * rstd * g[t]       + b[t]);
  out[pL(row, t + 256, 24)] = f2bf((v1 - mean) * rstd * g[t + 256] + b[t + 256]);
  out[pL(row, t + 512, 24)] = f2bf((v2 - mean) * rstd * g[t + 512] + b[t + 512]);
}

// ---------------- fp32 -> packed bf16 weights + bias concat ------------------------
__global__ __launch_bounds__(256) void convert_kernel(
    const float* __restrict__ wu, const float* __restrict__ wq,
    const float* __restrict__ wk, const float* __restrict__ wv,
    const float* __restrict__ wo,
    const float* __restrict__ bu, const float* __restrict__ bq,
    const float* __restrict__ bk, const float* __restrict__ bv,
    short* __restrict__ Wb, float* __restrict__ bcat) {
  long i = (long)blockIdx.x * 256 + threadIdx.x;
  if (i < 5 * WElem) {
    int which = (int)(i / WElem);
    long off = i - (long)which * WElem;
    const float* src = which == 0 ? wu : which == 1 ? wq : which == 2 ? wk
                     : which == 3 ? wv : wo;
    int n = (int)(off / HD), k = (int)(off - (long)n * HD);
    Wb[(long)which * WElem + pL(n, k, 24)] = f2bf(src[off]);
  }
  if (i < 4 * HD) {
    int which = (int)(i / HD);
    int off = (int)(i - which * HD);
    const float* src = which == 0 ? bu : which == 1 ? bq : which == 2 ? bk : bv;
    bcat[i] = src[off];
  }
}

// ---------------- barrier-free streaming GEMM, 4 waves (2x2), wave tile 64x(TN*16) -
// 1-D grid, XCD-aware decode (flat%8 = XCD owns a contiguous by-stripe of 8).
// kf-major packed operands; ping-pong dist-2 prefetch; no LDS, no __syncthreads.
template <int EPI, int KF, int GZ, int TN>
__global__ __launch_bounds__(256, 3) void wgemm(
    const short* __restrict__ Ag, const short* __restrict__ Bg,
    long sAz, long sBz,
    short* __restrict__ o0, short* __restrict__ o1,
    short* __restrict__ o2, short* __restrict__ o3,
    float* __restrict__ outf, const float* __restrict__ bias,
    const short* __restrict__ umul) {
  constexpr int TM = 4;
  int f = blockIdx.x;
  int xcd = f & 7, i = f >> 3;
  int bx = i >> 3, byo = i & 7;
  int z, by;
  if constexpr (GZ == 1) { z = 0;        by = xcd * 8 + byo; }
  else                   { z = xcd >> 1; by = (xcd & 1) * 8 + byo; }

  int t = threadIdx.x, w = t >> 6, lane = t & 63;
  int qd = lane >> 4, l15 = lane & 15;
  int mf0 = (by * 2 + (w >> 1)) * TM;          // frag-row index (strip-aligned)
  int nf0 = (bx * 2 + (w & 1)) * TN;           // frag-col index
  // strip bases in kf-major pack; bSub folds the half-strip offset for TN=2
  const short* aB = Ag + (long)z * sAz + (long)(mf0 >> 2) * KF * 2048 + lane * 8;
  const short* bB = Bg + (long)z * sBz + (long)(nf0 >> 2) * KF * 2048 +
                    (nf0 & 3) * 512 + lane * 8;

  floatx4 acc[TM][TN] = {};
  short8 a[2][TM], b[2][TN];

#define LOADF(p, kf)                                                        \
  {                                                                         \
    _Pragma("unroll") for (int mi = 0; mi < TM; mi++)                       \
        a[p][mi] = *(const short8*)(aB + ((kf) * 4 + mi) * 512);            \
    _Pragma("unroll") for (int ni = 0; ni < TN; ni++)                       \
        b[p][ni] = *(const short8*)(bB + ((kf) * 4 + ni) * 512);            \
  }
#define MFMAS(p)                                                            \
  {                                                                         \
    _Pragma("unroll") for (int mi = 0; mi < TM; mi++)                       \
        _Pragma("unroll") for (int ni = 0; ni < TN; ni++)                   \
            acc[mi][ni] = __builtin_amdgcn_mfma_f32_16x16x32_bf16(          \
                a[p][mi], b[p][ni], acc[mi][ni], 0, 0, 0);                  \
  }

  LOADF(0, 0);
  LOADF(1, 1);
#pragma unroll 2
  for (int kf = 0; kf < KF; ++kf) {
    MFMAS(kf & 1);
    if (kf + 2 < KF) LOADF(kf & 1, kf + 2);   // refill the buffer just consumed
  }
#undef LOADF
#undef MFMAS

  // epilogue: lane holds D[row = qd*4+r][col = l15] per 16x16 frag
#pragma unroll
  for (int mi = 0; mi < TM; mi++)
#pragma unroll
    for (int ni = 0; ni < TN; ni++) {
      int mB = (mf0 + mi) * 16 + qd * 4;
      int col = (nf0 + ni) * 16 + l15;
#pragma unroll
      for (int r = 0; r < 4; r++) {
        int m = mB + r;
        float v = acc[mi][ni][r];
        if constexpr (EPI == 0) {
          v += bias[col];
          v = v / (1.0f + __expf(-v));  // silu
          short sv = f2bf(v);
          int which = col / HD;
          int d = col - which * HD;
          int batch = m >> 11, ii = m & (TT - 1);
          if (which == 0)      o0[(long)m * HD + d] = sv;                      // U row-major
          else if (which == 1) o1[(long)batch * QKpb + pL(ii, d, 24)] = sv;    // Q pack
          else if (which == 2) o2[(long)batch * QKpb + pL(ii, d, 24)] = sv;    // K pack
          else                 o3[(long)batch * QKpb + pL(d, ii, 64)] = sv;    // Vt pack
        } else if constexpr (EPI == 1) {
          v *= 0.022097086912079608f;   // 1/sqrt(2048)
          v = fmaxf(v, 0.0f);
          v = v * v;
          o0[(long)z * Ppb + pL(m, col, 64)] = f2bf(v);                        // P pack
        } else if constexpr (EPI == 2) {
          long gm = (long)z * TT + m;
          float um = bf2f(umul[gm * HD + col]);
          o0[pL((int)gm, col, 24)] = f2bf(v * um);                             // G pack
        } else {
          outf[(long)m * HD + col] = v + bias[col];
        }
      }
    }
}

extern "C" void kernel_launch(void* const* d_in, const int* in_sizes, int n_in,
                              void* d_out, int out_size, void* d_ws, size_t ws_size,
                              hipStream_t stream) {
  (void)in_sizes; (void)n_in; (void)out_size; (void)ws_size;
  const float* hid = (const float*)d_in[0];
  const float* lng = (const float*)d_in[1];
  const float* lnb = (const float*)d_in[2];
  const float* Wu  = (const float*)d_in[3];
  const float* bu  = (const float*)d_in[4];
  const float* Wq  = (const float*)d_in[5];
  const float* bq  = (const float*)d_in[6];
  const float* Wk  = (const float*)d_in[7];
  const float* bk  = (const float*)d_in[8];
  const float* Wv  = (const float*)d_in[9];
  const float* bv  = (const float*)d_in[10];
  const float* Wo  = (const float*)d_in[11];
  const float* bo  = (const float*)d_in[12];

  // workspace layout (bytes); packed buffers
  char* ws = (char*)d_ws;
  short* Wb   = (short*)(ws);                 // 5*589824 bf16 = 5,898,240 B (packed)
  float* bcat = (float*)(ws + 5898240);       // 3072 fp32     =    12,288 B
  short* xbf  = (short*)(ws + 5910528);       // x pack, 12,582,912 B
  short* Ub   = (short*)(ws + 18493440);      // U row-major, 12,582,912 B
  short* Qb   = (short*)(ws + 31076352);      // Q pack, 12,582,912 B
  short* Kb   = (short*)(ws + 43659264);      // K pack, 12,582,912 B
  short* Vt   = (short*)(ws + 56242176);      // Vt pack, 12,582,912 B
  short* Pb   = (short*)(ws + 68825088);      // P pack, 33,554,432 B
  short* Gb   = (short*)(ws + 102379520);     // G pack, 12,582,912 B (total ~115 MB)

  convert_kernel<<<11520, 256, 0, stream>>>(Wu, Wq, Wk, Wv, Wo, bu, bq, bk, bv, Wb, bcat);
  ln_kernel<<<8192, 256, 0, stream>>>(hid, lng, lnb, xbf);

  // U,Q,K,V = silu(x @ Wcat^T + bcat): GY=64, GX=24, GZ=1; wave 64x64
  wgemm<0, 24, 1, 4><<<1536, 256, 0, stream>>>(
      xbf, Wb, 0, 0, Ub, Qb, Kb, Vt, nullptr, bcat, nullptr);

  // P = relu(QK^T/sqrt(T))^2 per batch: GY=16, GX=16, GZ=4; wave 64x64
  wgemm<1, 24, 4, 4><<<1024, 256, 0, stream>>>(
      Qb, Kb, QKpb, QKpb, Pb, nullptr, nullptr, nullptr, nullptr, nullptr, nullptr);

  // G = (P @ V) * U per batch: GY=16, GX=12, GZ=4; wave 64x32 (768 blocks)
  wgemm<2, 64, 4, 2><<<768, 256, 0, stream>>>(
      Pb, Vt, Ppb, QKpb, Gb, nullptr, nullptr, nullptr, nullptr, nullptr, Ub);

  // out = G @ Wo^T + bo: GY=64, GX=12, GZ=1; wave 64x32 (768 blocks), fp32 out
  wgemm<3, 24, 1, 2><<<768, 256, 0, stream>>>(
      Gb, Wb + 4 * WElem, 0, 0, nullptr, nullptr, nullptr, nullptr,
      (float*)d_out, bo, nullptr);
}

// Round 10
// 275.450 us; speedup vs baseline: 1.2888x; 1.0032x over previous
//
#include <hip/hip_runtime.h>
#include <math.h>

// GAU attention: LN -> silu(x@W^T+b) x4 -> P=relu^2(QK^T/sqrt(T)) -> AV=P@V -> (U*AV)@Wo^T+bo
// R10: R9 (kf-major packed register streaming, XCD remap, dist-2 ping-pong) +
//  1) ni-outer MFMA order: first MFMA group needs loads #1-5 of 8 (A0-3,B0) ->
//     progressive vmcnt(3..0) instead of draining all 8 loads per iter (R9 bug).
//  2) 1x4 wave arrangement (WN=4) for QKVU/P: all 4 waves read the SAME
//     A-frags (4KB/iter, L1-resident) -> 3/4 of A-loads become L1 hits,
//     halving unique-A L2 traffic. AV/out keep 2x2 (WN=2, TN=2).

typedef __attribute__((ext_vector_type(8))) short short8;
typedef __attribute__((ext_vector_type(4))) float floatx4;

constexpr int HD = 768;
constexpr int TT = 2048;
constexpr long WElem = 589824;     // 768*768
constexpr long QKpb  = 1572864;    // 2048*768 shorts per batch
constexpr long Ppb   = 4194304;    // 2048*2048 shorts per batch

__device__ __forceinline__ short f2bf(float x) {
  unsigned u = __builtin_bit_cast(unsigned, x);
  u = u + 0x7fffu + ((u >> 16) & 1u);   // RNE
  return (short)(u >> 16);
}
__device__ __forceinline__ float bf2f(short s) {
  unsigned u = ((unsigned)(unsigned short)s) << 16;
  return __builtin_bit_cast(float, u);
}

// kf-major packed offset (in shorts) of element (i, c) of a row-major [R x C]
// matrix, KF = C/32. Layout: [strip = i>>6][kf = c>>5][frag mi = (i>>4)&3][512].
// Within-frag: lane = ((c&31)>>3)*16 + (i&15), elem = c&7.
__device__ __forceinline__ long pL(int i, int c, int KF) {
  return (((long)(i >> 6) * KF + (c >> 5)) * 4 + ((i >> 4) & 3)) * 512 +
         ((c & 31) >> 3) * 128 + (i & 15) * 8 + (c & 7);
}

// ---------------- LayerNorm + bf16 cast, writes x in packed-frag order ------------
__global__ __launch_bounds__(256) void ln_kernel(
    const float* __restrict__ x, const float* __restrict__ g,
    const float* __restrict__ b, short* __restrict__ out) {
  int row = blockIdx.x;
  const float* xr = x + (long)row * HD;
  int t = threadIdx.x;
  float v0 = xr[t], v1 = xr[t + 256], v2 = xr[t + 512];
  float s = v0 + v1 + v2;
  float ss = v0 * v0 + v1 * v1 + v2 * v2;
#pragma unroll
  for (int o = 32; o > 0; o >>= 1) {
    s += __shfl_down(s, o);
    ss += __shfl_down(ss, o);
  }
  __shared__ float red[8];
  int wid = t >> 6;
  if ((t & 63) == 0) { red[wid] = s; red[4 + wid] = ss; }
  __syncthreads();
  float S = red[0] + red[1] + red[2] + red[3];
  float SS = red[4] + red[5] + red[6] + red[7];
  float mean = S * (1.0f / HD);
  float var = SS * (1.0f / HD) - mean * mean;
  float rstd = rsqrtf(var + 1e-5f);
  out[pL(row, t, 24)]       = f2bf((v0 - mean) * rstd * g[t]       + b[t]);
  out[pL(row, t + 256, 24)] = f2bf((v1 - mean) * rstd * g[t + 256] + b[t + 256]);
  out[pL(row, t + 512, 24)] = f2bf((v2 - mean) * rstd * g[t + 512] + b[t + 512]);
}

// ---------------- fp32 -> packed bf16 weights + bias concat ------------------------
__global__ __launch_bounds__(256) void convert_kernel(
    const float* __restrict__ wu, const float* __restrict__ wq,
    const float* __restrict__ wk, const float* __restrict__ wv,
    const float* __restrict__ wo,
    const float* __restrict__ bu, const float* __restrict__ bq,
    const float* __restrict__ bk, const float* __restrict__ bv,
    short* __restrict__ Wb, float* __restrict__ bcat) {
  long i = (long)blockIdx.x * 256 + threadIdx.x;
  if (i < 5 * WElem) {
    int which = (int)(i / WElem);
    long off = i - (long)which * WElem;
    const float* src = which == 0 ? wu : which == 1 ? wq : which == 2 ? wk
                     : which == 3 ? wv : wo;
    int n = (int)(off / HD), k = (int)(off - (long)n * HD);
    Wb[(long)which * WElem + pL(n, k, 24)] = f2bf(src[off]);
  }
  if (i < 4 * HD) {
    int which = (int)(i / HD);
    int off = (int)(i - which * HD);
    const float* src = which == 0 ? bu : which == 1 ? bq : which == 2 ? bk : bv;
    bcat[i] = src[off];
  }
}

// ---------------- barrier-free streaming GEMM ---------------------------------------
// 4 waves arranged WM x WN (WM = 4/WN); wave tile 64 x (TN*16).
// 1-D grid, XCD-aware decode (flat%8 = XCD owns a contiguous by-stripe).
// kf-major packed operands; dist-2 ping-pong; ni-outer MFMA (progressive vmcnt).
template <int EPI, int KF, int GZ, int TN, int WN, int GY>
__global__ __launch_bounds__(256, 3) void wgemm(
    const short* __restrict__ Ag, const short* __restrict__ Bg,
    long sAz, long sBz,
    short* __restrict__ o0, short* __restrict__ o1,
    short* __restrict__ o2, short* __restrict__ o3,
    float* __restrict__ outf, const float* __restrict__ bias,
    const short* __restrict__ umul) {
  constexpr int TM = 4;
  constexpr int WM = 4 / WN;
  constexpr int GYX = (GZ == 1) ? GY / 8 : GY / 2;   // by-range per XCD
  int f = blockIdx.x;
  int xcd = f & 7, i = f >> 3;
  int bx = i / GYX, byo = i % GYX;
  int z, by;
  if constexpr (GZ == 1) { z = 0;        by = xcd * GYX + byo; }
  else                   { z = xcd >> 1; by = (xcd & 1) * GYX + byo; }

  int t = threadIdx.x, w = t >> 6, lane = t & 63;
  int qd = lane >> 4, l15 = lane & 15;
  int wm = w / WN, wn = w % WN;
  int mf0 = (by * WM + wm) * TM;               // frag-row index (strip-aligned)
  int nf0 = (bx * WN + wn) * TN;               // frag-col index
  const short* aB = Ag + (long)z * sAz + (long)(mf0 >> 2) * KF * 2048 + lane * 8;
  const short* bB = Bg + (long)z * sBz + (long)(nf0 >> 2) * KF * 2048 +
                    (nf0 & 3) * 512 + lane * 8;

  floatx4 acc[TM][TN] = {};
  short8 a[2][TM], b[2][TN];

#define LOADF(p, kf)                                                        \
  {                                                                         \
    _Pragma("unroll") for (int mi = 0; mi < TM; mi++)                       \
        a[p][mi] = *(const short8*)(aB + ((kf) * 4 + mi) * 512);            \
    _Pragma("unroll") for (int ni = 0; ni < TN; ni++)                       \
        b[p][ni] = *(const short8*)(bB + ((kf) * 4 + ni) * 512);            \
  }
  // ni-outer: group ni needs a0..a3 + b[ni] -> first MFMA after 5 of 8 loads
#define MFMAS(p)                                                            \
  {                                                                         \
    _Pragma("unroll") for (int ni = 0; ni < TN; ni++)                       \
        _Pragma("unroll") for (int mi = 0; mi < TM; mi++)                   \
            acc[mi][ni] = __builtin_amdgcn_mfma_f32_16x16x32_bf16(          \
                a[p][mi], b[p][ni], acc[mi][ni], 0, 0, 0);                  \
  }

  LOADF(0, 0);
  LOADF(1, 1);
#pragma unroll 2
  for (int kf = 0; kf < KF; ++kf) {
    MFMAS(kf & 1);
    if (kf + 2 < KF) LOADF(kf & 1, kf + 2);   // refill the buffer just consumed
  }
#undef LOADF
#undef MFMAS

  // epilogue: lane holds D[row = qd*4+r][col = l15] per 16x16 frag
#pragma unroll
  for (int mi = 0; mi < TM; mi++)
#pragma unroll
    for (int ni = 0; ni < TN; ni++) {
      int mB = (mf0 + mi) * 16 + qd * 4;
      int col = (nf0 + ni) * 16 + l15;
#pragma unroll
      for (int r = 0; r < 4; r++) {
        int m = mB + r;
        float v = acc[mi][ni][r];
        if constexpr (EPI == 0) {
          v += bias[col];
          v = v / (1.0f + __expf(-v));  // silu
          short sv = f2bf(v);
          int which = col / HD;
          int d = col - which * HD;
          int batch = m >> 11, ii = m & (TT - 1);
          if (which == 0)      o0[(long)m * HD + d] = sv;                      // U row-major
          else if (which == 1) o1[(long)batch * QKpb + pL(ii, d, 24)] = sv;    // Q pack
          else if (which == 2) o2[(long)batch * QKpb + pL(ii, d, 24)] = sv;    // K pack
          else                 o3[(long)batch * QKpb + pL(d, ii, 64)] = sv;    // Vt pack
        } else if constexpr (EPI == 1) {
          v *= 0.022097086912079608f;   // 1/sqrt(2048)
          v = fmaxf(v, 0.0f);
          v = v * v;
          o0[(long)z * Ppb + pL(m, col, 64)] = f2bf(v);                        // P pack
        } else if constexpr (EPI == 2) {
          long gm = (long)z * TT + m;
          float um = bf2f(umul[gm * HD + col]);
          o0[pL((int)gm, col, 24)] = f2bf(v * um);                             // G pack
        } else {
          outf[(long)m * HD + col] = v + bias[col];
        }
      }
    }
}

extern "C" void kernel_launch(void* const* d_in, const int* in_sizes, int n_in,
                              void* d_out, int out_size, void* d_ws, size_t ws_size,
                              hipStream_t stream) {
  (void)in_sizes; (void)n_in; (void)out_size; (void)ws_size;
  const float* hid = (const float*)d_in[0];
  const float* lng = (const float*)d_in[1];
  const float* lnb = (const float*)d_in[2];
  const float* Wu  = (const float*)d_in[3];
  const float* bu  = (const float*)d_in[4];
  const float* Wq  = (const float*)d_in[5];
  const float* bq  = (const float*)d_in[6];
  const float* Wk  = (const float*)d_in[7];
  const float* bk  = (const float*)d_in[8];
  const float* Wv  = (const float*)d_in[9];
  const float* bv  = (const float*)d_in[10];
  const float* Wo  = (const float*)d_in[11];
  const float* bo  = (const float*)d_in[12];

  // workspace layout (bytes); packed buffers
  char* ws = (char*)d_ws;
  short* Wb   = (short*)(ws);                 // 5*589824 bf16 = 5,898,240 B (packed)
  float* bcat = (float*)(ws + 5898240);       // 3072 fp32     =    12,288 B
  short* xbf  = (short*)(ws + 5910528);       // x pack, 12,582,912 B
  short* Ub   = (short*)(ws + 18493440);      // U row-major, 12,582,912 B
  short* Qb   = (short*)(ws + 31076352);      // Q pack, 12,582,912 B
  short* Kb   = (short*)(ws + 43659264);      // K pack, 12,582,912 B
  short* Vt   = (short*)(ws + 56242176);      // Vt pack, 12,582,912 B
  short* Pb   = (short*)(ws + 68825088);      // P pack, 33,554,432 B
  short* Gb   = (short*)(ws + 102379520);     // G pack, 12,582,912 B (total ~115 MB)

  convert_kernel<<<11520, 256, 0, stream>>>(Wu, Wq, Wk, Wv, Wo, bu, bq, bk, bv, Wb, bcat);
  ln_kernel<<<8192, 256, 0, stream>>>(hid, lng, lnb, xbf);

  // U,Q,K,V = silu(x @ Wcat^T + bcat): block 64x256 (1x4 waves), GY=128, GX=12
  wgemm<0, 24, 1, 4, 4, 128><<<1536, 256, 0, stream>>>(
      xbf, Wb, 0, 0, Ub, Qb, Kb, Vt, nullptr, bcat, nullptr);

  // P = relu(QK^T/sqrt(T))^2 per batch: block 64x256 (1x4), GY=32, GX=8, GZ=4
  wgemm<1, 24, 4, 4, 4, 32><<<1024, 256, 0, stream>>>(
      Qb, Kb, QKpb, QKpb, Pb, nullptr, nullptr, nullptr, nullptr, nullptr, nullptr);

  // G = (P @ V) * U per batch: block 128x64 (2x2, TN=2), GY=16, GX=12, GZ=4
  wgemm<2, 64, 4, 2, 2, 16><<<768, 256, 0, stream>>>(
      Pb, Vt, Ppb, QKpb, Gb, nullptr, nullptr, nullptr, nullptr, nullptr, Ub);

  // out = G @ Wo^T + bo: block 128x64 (2x2, TN=2), GY=64, GX=12, GZ=1, fp32 out
  wgemm<3, 24, 1, 2, 2, 64><<<768, 256, 0, stream>>>(
      Gb, Wb + 4 * WElem, 0, 0, nullptr, nullptr, nullptr, nullptr,
      (float*)d_out, bo, nullptr);
}

// Round 11
// 271.206 us; speedup vs baseline: 1.3090x; 1.0156x over previous
//
#include <hip/hip_runtime.h>
#include <math.h>

// GAU attention: LN -> silu(x@W^T+b) x4 -> P=relu^2(QK^T/sqrt(T)) -> AV=P@V -> (U*AV)@Wo^T+bo
// R11: de-confounded recombination of measured-best pieces:
//  - 2x2 wave arrangement, TN=4 (128x128 block) for QKVU and P  [R9: QKVU 70.7us;
//    R10's 1x4 raised unique bytes/block-iter 16->20KB and regressed 40%]
//  - ni-outer MFMA everywhere [R10: AV/out gained ~29us; first MFMA group waits
//    on 5 of 8 loads instead of 8]
//  - kf-major packed operands, dist-2 ping-pong, XCD remap, barrier-free K-loop.

typedef __attribute__((ext_vector_type(8))) short short8;
typedef __attribute__((ext_vector_type(4))) float floatx4;

constexpr int HD = 768;
constexpr int TT = 2048;
constexpr long WElem = 589824;     // 768*768
constexpr long QKpb  = 1572864;    // 2048*768 shorts per batch
constexpr long Ppb   = 4194304;    // 2048*2048 shorts per batch

__device__ __forceinline__ short f2bf(float x) {
  unsigned u = __builtin_bit_cast(unsigned, x);
  u = u + 0x7fffu + ((u >> 16) & 1u);   // RNE
  return (short)(u >> 16);
}
__device__ __forceinline__ float bf2f(short s) {
  unsigned u = ((unsigned)(unsigned short)s) << 16;
  return __builtin_bit_cast(float, u);
}

// kf-major packed offset (in shorts) of element (i, c) of a row-major [R x C]
// matrix, KF = C/32. Layout: [strip = i>>6][kf = c>>5][frag mi = (i>>4)&3][512].
// Within-frag: lane = ((c&31)>>3)*16 + (i&15), elem = c&7.
__device__ __forceinline__ long pL(int i, int c, int KF) {
  return (((long)(i >> 6) * KF + (c >> 5)) * 4 + ((i >> 4) & 3)) * 512 +
         ((c & 31) >> 3) * 128 + (i & 15) * 8 + (c & 7);
}

// ---------------- LayerNorm + bf16 cast, writes x in packed-frag order ------------
__global__ __launch_bounds__(256) void ln_kernel(
    const float* __restrict__ x, const float* __restrict__ g,
    const float* __restrict__ b, short* __restrict__ out) {
  int row = blockIdx.x;
  const float* xr = x + (long)row * HD;
  int t = threadIdx.x;
  float v0 = xr[t], v1 = xr[t + 256], v2 = xr[t + 512];
  float s = v0 + v1 + v2;
  float ss = v0 * v0 + v1 * v1 + v2 * v2;
#pragma unroll
  for (int o = 32; o > 0; o >>= 1) {
    s += __shfl_down(s, o);
    ss += __shfl_down(ss, o);
  }
  __shared__ float red[8];
  int wid = t >> 6;
  if ((t & 63) == 0) { red[wid] = s; red[4 + wid] = ss; }
  __syncthreads();
  float S = red[0] + red[1] + red[2] + red[3];
  float SS = red[4] + red[5] + red[6] + red[7];
  float mean = S * (1.0f / HD);
  float var = SS * (1.0f / HD) - mean * mean;
  float rstd = rsqrtf(var + 1e-5f);
  out[pL(row, t, 24)]       = f2bf((v0 - mean) * rstd * g[t]       + b[t]);
  out[pL(row, t + 256, 24)] = f2bf((v1 - mean) * rstd * g[t + 256] + b[t + 256]);
  out[pL(row, t + 512, 24)] = f2bf((v2 - mean) * rstd * g[t + 512] + b[t + 512]);
}

// ---------------- fp32 -> packed bf16 weights + bias concat ------------------------
__global__ __launch_bounds__(256) void convert_kernel(
    const float* __restrict__ wu, const float* __restrict__ wq,
    const float* __restrict__ wk, const float* __restrict__ wv,
    const float* __restrict__ wo,
    const float* __restrict__ bu, const float* __restrict__ bq,
    const float* __restrict__ bk, const float* __restrict__ bv,
    short* __restrict__ Wb, float* __restrict__ bcat) {
  long i = (long)blockIdx.x * 256 + threadIdx.x;
  if (i < 5 * WElem) {
    int which = (int)(i / WElem);
    long off = i - (long)which * WElem;
    const float* src = which == 0 ? wu : which == 1 ? wq : which == 2 ? wk
                     : which == 3 ? wv : wo;
    int n = (int)(off / HD), k = (int)(off - (long)n * HD);
    Wb[(long)which * WElem + pL(n, k, 24)] = f2bf(src[off]);
  }
  if (i < 4 * HD) {
    int which = (int)(i / HD);
    int off = (int)(i - which * HD);
    const float* src = which == 0 ? bu : which == 1 ? bq : which == 2 ? bk : bv;
    bcat[i] = src[off];
  }
}

// ---------------- barrier-free streaming GEMM ---------------------------------------
// 4 waves arranged WM x WN (WM = 4/WN); wave tile 64 x (TN*16).
// 1-D grid, XCD-aware decode (flat%8 = XCD owns a contiguous by-stripe).
// kf-major packed operands; dist-2 ping-pong; ni-outer MFMA (progressive vmcnt).
template <int EPI, int KF, int GZ, int TN, int WN, int GY>
__global__ __launch_bounds__(256, 3) void wgemm(
    const short* __restrict__ Ag, const short* __restrict__ Bg,
    long sAz, long sBz,
    short* __restrict__ o0, short* __restrict__ o1,
    short* __restrict__ o2, short* __restrict__ o3,
    float* __restrict__ outf, const float* __restrict__ bias,
    const short* __restrict__ umul) {
  constexpr int TM = 4;
  constexpr int WM = 4 / WN;
  constexpr int GYX = (GZ == 1) ? GY / 8 : GY / 2;   // by-range per XCD
  int f = blockIdx.x;
  int xcd = f & 7, i = f >> 3;
  int bx = i / GYX, byo = i % GYX;
  int z, by;
  if constexpr (GZ == 1) { z = 0;        by = xcd * GYX + byo; }
  else                   { z = xcd >> 1; by = (xcd & 1) * GYX + byo; }

  int t = threadIdx.x, w = t >> 6, lane = t & 63;
  int qd = lane >> 4, l15 = lane & 15;
  int wm = w / WN, wn = w % WN;
  int mf0 = (by * WM + wm) * TM;               // frag-row index (strip-aligned)
  int nf0 = (bx * WN + wn) * TN;               // frag-col index
  const short* aB = Ag + (long)z * sAz + (long)(mf0 >> 2) * KF * 2048 + lane * 8;
  const short* bB = Bg + (long)z * sBz + (long)(nf0 >> 2) * KF * 2048 +
                    (nf0 & 3) * 512 + lane * 8;

  floatx4 acc[TM][TN] = {};
  short8 a[2][TM], b[2][TN];

#define LOADF(p, kf)                                                        \
  {                                                                         \
    _Pragma("unroll") for (int mi = 0; mi < TM; mi++)                       \
        a[p][mi] = *(const short8*)(aB + ((kf) * 4 + mi) * 512);            \
    _Pragma("unroll") for (int ni = 0; ni < TN; ni++)                       \
        b[p][ni] = *(const short8*)(bB + ((kf) * 4 + ni) * 512);            \
  }
  // ni-outer: group ni needs a0..a3 + b[ni] -> first MFMA after 5 of 8 loads
#define MFMAS(p)                                                            \
  {                                                                         \
    _Pragma("unroll") for (int ni = 0; ni < TN; ni++)                       \
        _Pragma("unroll") for (int mi = 0; mi < TM; mi++)                   \
            acc[mi][ni] = __builtin_amdgcn_mfma_f32_16x16x32_bf16(          \
                a[p][mi], b[p][ni], acc[mi][ni], 0, 0, 0);                  \
  }

  LOADF(0, 0);
  LOADF(1, 1);
#pragma unroll 2
  for (int kf = 0; kf < KF; ++kf) {
    MFMAS(kf & 1);
    if (kf + 2 < KF) LOADF(kf & 1, kf + 2);   // refill the buffer just consumed
  }
#undef LOADF
#undef MFMAS

  // epilogue: lane holds D[row = qd*4+r][col = l15] per 16x16 frag
#pragma unroll
  for (int mi = 0; mi < TM; mi++)
#pragma unroll
    for (int ni = 0; ni < TN; ni++) {
      int mB = (mf0 + mi) * 16 + qd * 4;
      int col = (nf0 + ni) * 16 + l15;
#pragma unroll
      for (int r = 0; r < 4; r++) {
        int m = mB + r;
        float v = acc[mi][ni][r];
        if constexpr (EPI == 0) {
          v += bias[col];
          v = v / (1.0f + __expf(-v));  // silu
          short sv = f2bf(v);
          int which = col / HD;
          int d = col - which * HD;
          int batch = m >> 11, ii = m & (TT - 1);
          if (which == 0)      o0[(long)m * HD + d] = sv;                      // U row-major
          else if (which == 1) o1[(long)batch * QKpb + pL(ii, d, 24)] = sv;    // Q pack
          else if (which == 2) o2[(long)batch * QKpb + pL(ii, d, 24)] = sv;    // K pack
          else                 o3[(long)batch * QKpb + pL(d, ii, 64)] = sv;    // Vt pack
        } else if constexpr (EPI == 1) {
          v *= 0.022097086912079608f;   // 1/sqrt(2048)
          v = fmaxf(v, 0.0f);
          v = v * v;
          o0[(long)z * Ppb + pL(m, col, 64)] = f2bf(v);                        // P pack
        } else if constexpr (EPI == 2) {
          long gm = (long)z * TT + m;
          float um = bf2f(umul[gm * HD + col]);
          o0[pL((int)gm, col, 24)] = f2bf(v * um);                             // G pack
        } else {
          outf[(long)m * HD + col] = v + bias[col];
        }
      }
    }
}

extern "C" void kernel_launch(void* const* d_in, const int* in_sizes, int n_in,
                              void* d_out, int out_size, void* d_ws, size_t ws_size,
                              hipStream_t stream) {
  (void)in_sizes; (void)n_in; (void)out_size; (void)ws_size;
  const float* hid = (const float*)d_in[0];
  const float* lng = (const float*)d_in[1];
  const float* lnb = (const float*)d_in[2];
  const float* Wu  = (const float*)d_in[3];
  const float* bu  = (const float*)d_in[4];
  const float* Wq  = (const float*)d_in[5];
  const float* bq  = (const float*)d_in[6];
  const float* Wk  = (const float*)d_in[7];
  const float* bk  = (const float*)d_in[8];
  const float* Wv  = (const float*)d_in[9];
  const float* bv  = (const float*)d_in[10];
  const float* Wo  = (const float*)d_in[11];
  const float* bo  = (const float*)d_in[12];

  // workspace layout (bytes); packed buffers
  char* ws = (char*)d_ws;
  short* Wb   = (short*)(ws);                 // 5*589824 bf16 = 5,898,240 B (packed)
  float* bcat = (float*)(ws + 5898240);       // 3072 fp32     =    12,288 B
  short* xbf  = (short*)(ws + 5910528);       // x pack, 12,582,912 B
  short* Ub   = (short*)(ws + 18493440);      // U row-major, 12,582,912 B
  short* Qb   = (short*)(ws + 31076352);      // Q pack, 12,582,912 B
  short* Kb   = (short*)(ws + 43659264);      // K pack, 12,582,912 B
  short* Vt   = (short*)(ws + 56242176);      // Vt pack, 12,582,912 B
  short* Pb   = (short*)(ws + 68825088);      // P pack, 33,554,432 B
  short* Gb   = (short*)(ws + 102379520);     // G pack, 12,582,912 B (total ~115 MB)

  convert_kernel<<<11520, 256, 0, stream>>>(Wu, Wq, Wk, Wv, Wo, bu, bq, bk, bv, Wb, bcat);
  ln_kernel<<<8192, 256, 0, stream>>>(hid, lng, lnb, xbf);

  // U,Q,K,V = silu(x @ Wcat^T + bcat): block 128x128 (2x2), GY=64, GX=24
  wgemm<0, 24, 1, 4, 2, 64><<<1536, 256, 0, stream>>>(
      xbf, Wb, 0, 0, Ub, Qb, Kb, Vt, nullptr, bcat, nullptr);

  // P = relu(QK^T/sqrt(T))^2 per batch: block 128x128 (2x2), GY=16, GX=16, GZ=4
  wgemm<1, 24, 4, 4, 2, 16><<<1024, 256, 0, stream>>>(
      Qb, Kb, QKpb, QKpb, Pb, nullptr, nullptr, nullptr, nullptr, nullptr, nullptr);

  // G = (P @ V) * U per batch: block 128x64 (2x2, TN=2), GY=16, GX=12, GZ=4
  wgemm<2, 64, 4, 2, 2, 16><<<768, 256, 0, stream>>>(
      Pb, Vt, Ppb, QKpb, Gb, nullptr, nullptr, nullptr, nullptr, nullptr, Ub);

  // out = G @ Wo^T + bo: block 128x64 (2x2, TN=2), GY=64, GX=12, GZ=1, fp32 out
  wgemm<3, 24, 1, 2, 2, 64><<<768, 256, 0, stream>>>(
      Gb, Wb + 4 * WElem, 0, 0, nullptr, nullptr, nullptr, nullptr,
      (float*)d_out, bo, nullptr);
}